// Round 4
// baseline (831.923 us; speedup 1.0000x reference)
//
#include <hip/hip_runtime.h>
#include <math.h>

#define N_NODES 100000
#define N_EDGES 3200000
#define F_IN    512
#define HID     16
#define NCLS    7
#define ALPHA   0.1f
#define K_HOPS  10

// ---- workspace layout (4-byte element offsets); no aliasing ----
#define OFF_DEG     0u          // int[100000]
#define OFF_PART    100352u     // int[98]
#define OFF_CUR     101376u     // int[100000]
#define OFF_RP      202752u     // int[100001]
#define OFF_DINV    303104u     // float[100000]
#define OFF_COL     403456u     // int[3200000]
#define OFF_H0      3603456u    // float[100000*16]
#define OFF_H1      5203456u    // float[100000*16]
#define OFF_Z       6803456u    // float[100000*8]
// total = 7603456 elems = 30.4 MB

#define SCB 1024
#define SCG ((N_NODES + SCB - 1) / SCB)   // 98

// ---------------- deg: global per-node histogram of dst ----------------
__global__ void k_deg(const int* __restrict__ dst, int* __restrict__ deg) {
    int t = blockIdx.x * 256 + threadIdx.x;          // 800000 threads, 4 edges each
    const int4* d4 = (const int4*)dst;
    int4 d = d4[t];
    atomicAdd(&deg[d.x], 1);
    atomicAdd(&deg[d.y], 1);
    atomicAdd(&deg[d.z], 1);
    atomicAdd(&deg[d.w], 1);
}

// ---------------- scan phase 1: block-local exclusive scan + partials ----------------
__global__ void k_scan1(const int* __restrict__ deg, int* __restrict__ rp,
                        int* __restrict__ part) {
    __shared__ int s[SCB];
    int tid = threadIdx.x;
    int i = blockIdx.x * SCB + tid;
    int v = (i < N_NODES) ? deg[i] : 0;
    s[tid] = v;
    __syncthreads();
    for (int off = 1; off < SCB; off <<= 1) {
        int t = (tid >= off) ? s[tid - off] : 0;
        __syncthreads();
        s[tid] += t;
        __syncthreads();
    }
    if (i < N_NODES) rp[i] = s[tid] - v;             // block-local exclusive
    if (tid == SCB - 1) part[blockIdx.x] = s[tid];   // block total
}

// ---------------- scan phase 2: add block bases; emit rp/cur/dinv ----------------
__global__ void k_scan2(const int* __restrict__ part, const int* __restrict__ deg,
                        int* __restrict__ rp, int* __restrict__ cur,
                        float* __restrict__ dinv) {
    int b = blockIdx.x, tid = threadIdx.x;
    int i = b * SCB + tid;
    int base = 0;
    for (int j = 0; j < b; j++) base += part[j];     // <=97 uniform loads
    if (i < N_NODES) {
        int r = rp[i] + base;
        rp[i] = r;
        cur[i] = r;
        dinv[i] = rsqrtf((float)(deg[i] + 1));       // +1 = self loop
    }
    if (i == N_NODES) rp[N_NODES] = N_EDGES;
}

// ---------------- scatter: col[cur[dst]++] = src (col stays L2-resident) ----------------
__global__ void k_scat(const int* __restrict__ src, const int* __restrict__ dst,
                       int* __restrict__ cur, int* __restrict__ col) {
    int t = blockIdx.x * 256 + threadIdx.x;          // 800000 threads, 4 edges each
    const int4* s4 = (const int4*)src;
    const int4* d4 = (const int4*)dst;
    int4 s = s4[t];
    int4 d = d4[t];
    int p;
    p = atomicAdd(&cur[d.x], 1); col[p] = s.x;
    p = atomicAdd(&cur[d.y], 1); col[p] = s.y;
    p = atomicAdd(&cur[d.z], 1); col[p] = s.z;
    p = atomicAdd(&cur[d.w], 1); col[p] = s.w;
}

// ---------------- h0s = dinv * (x @ W1): LDS-tiled GEMM, b128 reads ----------------
// x tile stored row-major [64][36] (stride 36 floats: conflict-free float4 reads).
#define XW_ROWS 64
#define XW_KT   32
#define XW_S    36
#define XW_NT   (F_IN / XW_KT)   // 16 tiles
__global__ void k_xw1(const float* __restrict__ x, const float* __restrict__ W,
                      const float* __restrict__ dinv, float* __restrict__ h0s) {
    __shared__ float xT[2][XW_ROWS * XW_S];
    int tid = threadIdx.x;
    int rowBase = blockIdx.x * XW_ROWS;

    int rf0 = tid >> 3, kq = tid & 7;    // row 0..31, float4-col 0..7
    int rf1 = rf0 + 32;
    bool v0 = (rowBase + rf0) < N_NODES;
    bool v1 = (rowBase + rf1) < N_NODES;
    const float4* xrow0 = (const float4*)(x + (size_t)(rowBase + rf0) * F_IN);
    const float4* xrow1 = (const float4*)(x + (size_t)(rowBase + rf1) * F_IN);

    int r  = tid & 63;
    int cg = __builtin_amdgcn_readfirstlane(tid >> 6);   // wave-uniform -> s_load W
    const float4* W4 = (const float4*)W;

    float4 zero4 = make_float4(0.f, 0.f, 0.f, 0.f);
    float4 acc = zero4;
    float4 ld0 = v0 ? xrow0[kq] : zero4;
    float4 ld1 = v1 ? xrow1[kq] : zero4;

    for (int kt = 0; kt < XW_NT; kt++) {
        float* xb = xT[kt & 1];
        *(float4*)&xb[rf0 * XW_S + kq * 4] = ld0;
        *(float4*)&xb[rf1 * XW_S + kq * 4] = ld1;
        if (kt + 1 < XW_NT) {
            ld0 = v0 ? xrow0[(kt + 1) * 8 + kq] : zero4;
            ld1 = v1 ? xrow1[(kt + 1) * 8 + kq] : zero4;
        }
        __syncthreads();
        const float* xr = &xb[r * XW_S];
#pragma unroll
        for (int k8 = 0; k8 < 8; k8++) {
            float4 xv = *(const float4*)&xr[k8 * 4];
            float4 w0 = W4[(kt * XW_KT + k8 * 4 + 0) * 4 + cg];
            acc.x += xv.x * w0.x; acc.y += xv.x * w0.y;
            acc.z += xv.x * w0.z; acc.w += xv.x * w0.w;
            float4 w1 = W4[(kt * XW_KT + k8 * 4 + 1) * 4 + cg];
            acc.x += xv.y * w1.x; acc.y += xv.y * w1.y;
            acc.z += xv.y * w1.z; acc.w += xv.y * w1.w;
            float4 w2 = W4[(kt * XW_KT + k8 * 4 + 2) * 4 + cg];
            acc.x += xv.z * w2.x; acc.y += xv.z * w2.y;
            acc.z += xv.z * w2.z; acc.w += xv.z * w2.w;
            float4 w3 = W4[(kt * XW_KT + k8 * 4 + 3) * 4 + cg];
            acc.x += xv.w * w3.x; acc.y += xv.w * w3.y;
            acc.z += xv.w * w3.z; acc.w += xv.w * w3.w;
        }
        __syncthreads();
    }
    int node = rowBase + r;
    if (node < N_NODES) {
        float dv = dinv[node];
        float4 o;
        o.x = dv * acc.x; o.y = dv * acc.y; o.z = dv * acc.z; o.w = dv * acc.w;
        ((float4*)h0s)[(size_t)node * 4 + cg] = o;
    }
}

// ---------------- aggregate 1: one wave per node ----------------
// lane = c + 16*eo; unroll x2 with in-order adds (bitwise identical order).
__global__ void k_agg1(const float* __restrict__ h0s, const int* __restrict__ rp,
                       const int* __restrict__ col, const float* __restrict__ dinv,
                       const float* __restrict__ b1, float* __restrict__ h1) {
    int node = (blockIdx.x * blockDim.x + threadIdx.x) >> 6;
    if (node >= N_NODES) return;
    int lane = threadIdx.x & 63;
    int c = lane & 15, eo = lane >> 4;
    int e0 = rp[node], e1 = rp[node + 1];
    float acc = 0.f;
    int e = e0 + eo;
    for (; e + 4 < e1; e += 8) {
        int c0 = col[e];
        int c1 = col[e + 4];
        float v0 = h0s[(size_t)c0 * HID + c];
        float v1 = h0s[(size_t)c1 * HID + c];
        acc += v0;
        acc += v1;
    }
    if (e < e1) acc += h0s[(size_t)col[e] * HID + c];
    acc += __shfl_xor(acc, 16);
    acc += __shfl_xor(acc, 32);
    float o = dinv[node] * (acc + h0s[(size_t)node * HID + c]) + b1[c];
    if (eo == 0) h1[(size_t)node * HID + c] = fmaxf(o, 0.f);
}

// ---------------- 10 fused hops + zs = dinv * (h @ W2) ----------------
__global__ void k_hops(const float* __restrict__ h1, const float* __restrict__ Wl,
                       const float* __restrict__ bl, const float* __restrict__ W2,
                       const float* __restrict__ dinv, float* __restrict__ zs) {
    int node = blockIdx.x * blockDim.x + threadIdx.x;
    if (node >= N_NODES) return;
    float h[HID];
    const float4* h4 = (const float4*)(h1 + (size_t)node * HID);
#pragma unroll
    for (int q = 0; q < HID / 4; q++) {
        float4 v = h4[q];
        h[q * 4 + 0] = v.x; h[q * 4 + 1] = v.y;
        h[q * 4 + 2] = v.z; h[q * 4 + 3] = v.w;
    }
    for (int it = 0; it < K_HOPS; it++) {
        float tm[HID];
#pragma unroll
        for (int c = 0; c < HID; c++) tm[c] = bl[c];
#pragma unroll
        for (int k = 0; k < HID; k++) {
            float hk = h[k];
#pragma unroll
            for (int c = 0; c < HID; c++) tm[c] += hk * Wl[k * HID + c];
        }
#pragma unroll
        for (int c = 0; c < HID; c++)
            h[c] = ALPHA * fmaxf(tm[c], 0.f) + (1.f - ALPHA) * h[c];
    }
    float dv = dinv[node];
    float zz[8];
#pragma unroll
    for (int c = 0; c < 8; c++) zz[c] = 0.f;
#pragma unroll
    for (int k = 0; k < HID; k++) {
        float hk = h[k];
#pragma unroll
        for (int c = 0; c < NCLS; c++) zz[c] += hk * W2[k * NCLS + c];
    }
    float4* z4 = (float4*)(zs + (size_t)node * 8);
    float4 v0, v1;
    v0.x = dv * zz[0]; v0.y = dv * zz[1]; v0.z = dv * zz[2]; v0.w = dv * zz[3];
    v1.x = dv * zz[4]; v1.y = dv * zz[5]; v1.z = dv * zz[6]; v1.w = 0.f;
    z4[0] = v0; z4[1] = v1;
}

// ---------------- aggregate 2 + log_softmax: one wave per node ----------------
// lane = c + 8*eo; unroll x2 with in-order adds.
__global__ void k_agg2(const float* __restrict__ zs, const int* __restrict__ rp,
                       const int* __restrict__ col, const float* __restrict__ dinv,
                       const float* __restrict__ b2, float* __restrict__ out) {
    int node = (blockIdx.x * blockDim.x + threadIdx.x) >> 6;
    if (node >= N_NODES) return;
    int lane = threadIdx.x & 63;
    int c = lane & 7, eo = lane >> 3;
    int e0 = rp[node], e1 = rp[node + 1];
    float acc = 0.f;
    int e = e0 + eo;
    for (; e + 8 < e1; e += 16) {
        int c0 = col[e];
        int c1 = col[e + 8];
        float v0 = zs[(size_t)c0 * 8 + c];
        float v1 = zs[(size_t)c1 * 8 + c];
        acc += v0;
        acc += v1;
    }
    if (e < e1) acc += zs[(size_t)col[e] * 8 + c];
    acc += __shfl_xor(acc, 8);
    acc += __shfl_xor(acc, 16);
    acc += __shfl_xor(acc, 32);
    float o = dinv[node] * (acc + zs[(size_t)node * 8 + c]) + ((c < NCLS) ? b2[c] : 0.f);
    float val = (c < NCLS) ? o : -INFINITY;
    float m = val;
    m = fmaxf(m, __shfl_xor(m, 1));
    m = fmaxf(m, __shfl_xor(m, 2));
    m = fmaxf(m, __shfl_xor(m, 4));
    float ex = (c < NCLS) ? expf(o - m) : 0.f;
    float ss = ex;
    ss += __shfl_xor(ss, 1);
    ss += __shfl_xor(ss, 2);
    ss += __shfl_xor(ss, 4);
    if (eo == 0 && c < NCLS) out[(size_t)node * NCLS + c] = o - m - logf(ss);
}

extern "C" void kernel_launch(void* const* d_in, const int* in_sizes, int n_in,
                              void* d_out, int out_size, void* d_ws, size_t ws_size,
                              hipStream_t stream) {
    const float* x  = (const float*)d_in[0];
    const int*   ei = (const int*)d_in[1];
    const float* W1 = (const float*)d_in[2];
    const float* b1 = (const float*)d_in[3];
    const float* Wl = (const float*)d_in[4];
    const float* bl = (const float*)d_in[5];
    const float* W2 = (const float*)d_in[6];
    const float* b2 = (const float*)d_in[7];
    float* out = (float*)d_out;

    int*   wsI = (int*)d_ws;
    float* wsF = (float*)d_ws;
    int*   deg  = wsI + OFF_DEG;
    int*   part = wsI + OFF_PART;
    int*   cur  = wsI + OFF_CUR;
    int*   rp   = wsI + OFF_RP;
    float* dinv = wsF + OFF_DINV;
    int*   col  = wsI + OFF_COL;
    float* h0s  = wsF + OFF_H0;
    float* h1   = wsF + OFF_H1;
    float* zs   = wsF + OFF_Z;

    const int* src = ei;
    const int* dst = ei + N_EDGES;

    hipMemsetAsync(deg, 0, N_NODES * sizeof(int), stream);

    k_deg<<<(N_EDGES / 4) / 256, 256, 0, stream>>>(dst, deg);
    k_scan1<<<SCG, SCB, 0, stream>>>(deg, rp, part);
    k_scan2<<<SCG, SCB, 0, stream>>>(part, deg, rp, cur, dinv);
    k_scat<<<(N_EDGES / 4) / 256, 256, 0, stream>>>(src, dst, cur, col);
    k_xw1<<<(N_NODES + XW_ROWS - 1) / XW_ROWS, 256, 0, stream>>>(x, W1, dinv, h0s);
    k_agg1<<<(N_NODES * 64 + 255) / 256, 256, 0, stream>>>(h0s, rp, col, dinv, b1, h1);
    k_hops<<<(N_NODES + 255) / 256, 256, 0, stream>>>(h1, Wl, bl, W2, dinv, zs);
    k_agg2<<<(N_NODES * 64 + 255) / 256, 256, 0, stream>>>(zs, rp, col, dinv, b2, out);
}

// Round 5
// 567.997 us; speedup vs baseline: 1.4647x; 1.4647x over previous
//
#include <hip/hip_runtime.h>
#include <math.h>

#define N_NODES 100000
#define N_EDGES 3200000
#define F_IN    512
#define HID     16
#define NCLS    7
#define ALPHA   0.1f
#define K_HOPS  10

// bucketing: 128 nodes per bucket
#define SHIFT   7
#define BWIDTH  128
#define NBUCK   ((N_NODES + BWIDTH - 1) / BWIDTH)   // 782
#define CHUNK   4096
#define BIN_T   512
#define EPT     (CHUNK / BIN_T)                      // 8 edges per thread
#define A3_BLOCKS ((N_EDGES + CHUNK - 1) / CHUNK)   // 782

// ---- workspace layout (4-byte element offsets); no aliasing ----
#define OFF_BCNT    0u          // int[782]
#define OFF_BSTART  1024u       // int[783]
#define OFF_BCUR    2048u       // int[782]
#define OFF_RP      3072u       // int[100001]
#define OFF_DINV    103424u     // float[100000]
#define OFF_COL     203776u     // int[3200000]
#define OFF_BINNED  3403776u    // uint[3200000]
#define OFF_H0      6603776u    // float[100000*16]
#define OFF_H1      8203776u    // float[100000*16]
#define OFF_Z       9803776u    // float[100000*8]

// ---------------- A1: global bucket histogram ----------------
__global__ void k_bhist(const int* __restrict__ dst, int* __restrict__ bcnt) {
    __shared__ int h[NBUCK];
    int tid = threadIdx.x;
    for (int i = tid; i < NBUCK; i += 256) h[i] = 0;
    __syncthreads();
    for (int e = blockIdx.x * 256 + tid; e < N_EDGES; e += gridDim.x * 256)
        atomicAdd(&h[dst[e] >> SHIFT], 1);
    __syncthreads();
    for (int i = tid; i < NBUCK; i += 256) {
        int v = h[i];
        if (v) atomicAdd(&bcnt[i], v);
    }
}

// ---------------- A2: scan bucket counts ----------------
__global__ void k_bscan(const int* __restrict__ bcnt, int* __restrict__ bstart,
                        int* __restrict__ bcur) {
    __shared__ int s[1024];
    int tid = threadIdx.x;
    int v = (tid < NBUCK) ? bcnt[tid] : 0;
    s[tid] = v;
    __syncthreads();
    for (int off = 1; off < 1024; off <<= 1) {
        int t = (tid >= off) ? s[tid - off] : 0;
        __syncthreads();
        s[tid] += t;
        __syncthreads();
    }
    if (tid < NBUCK) {
        int ex = s[tid] - v;     // exclusive
        bstart[tid] = ex;
        bcur[tid] = ex;
    }
    if (tid == 0) bstart[NBUCK] = N_EDGES;
}

// ---------------- A3: binned scatter of packed edges ----------------
// 512 threads, CHUNK 4096 -> 782 blocks (6 waves/SIMD), chain depth 8.
__global__ void __launch_bounds__(BIN_T)
k_bin(const int* __restrict__ src, const int* __restrict__ dst,
      int* __restrict__ bcur, unsigned int* __restrict__ binned) {
    __shared__ int ha[NBUCK];
    __shared__ int gbase[NBUCK];
    __shared__ int lcur[NBUCK];
    int tid = threadIdx.x;
    int e0 = blockIdx.x * CHUNK;
    int e1 = e0 + CHUNK;
    if (e1 > N_EDGES) e1 = N_EDGES;
    for (int i = tid; i < NBUCK; i += BIN_T) ha[i] = 0;
    __syncthreads();
    int dloc[EPT];
#pragma unroll
    for (int i = 0; i < EPT; i++) {
        int e = e0 + tid + i * BIN_T;
        dloc[i] = (e < e1) ? dst[e] : -1;
        if (dloc[i] >= 0) atomicAdd(&ha[dloc[i] >> SHIFT], 1);
    }
    __syncthreads();
    for (int s = tid; s < NBUCK; s += BIN_T) {
        int c = ha[s];
        lcur[s] = 0;
        gbase[s] = c ? atomicAdd(&bcur[s], c) : 0;
    }
    __syncthreads();
#pragma unroll
    for (int i = 0; i < EPT; i++) {
        int d = dloc[i];
        if (d >= 0) {
            int e = e0 + tid + i * BIN_T;
            int bk = d >> SHIFT;
            int idx = atomicAdd(&lcur[bk], 1);
            binned[gbase[bk] + idx] =
                ((unsigned int)(d & (BWIDTH - 1)) << 17) | (unsigned int)src[e];
        }
    }
}

// ---------------- B: per-bucket CSR (count, scan, rp/dinv, col scatter) ----------------
// 512 threads -> 6 waves/SIMD, per-thread chain depth halved.
__global__ void __launch_bounds__(512)
k_csr(const unsigned int* __restrict__ binned, const int* __restrict__ bstart,
      int* __restrict__ rp, float* __restrict__ dinv, int* __restrict__ col) {
    __shared__ int cnt[BWIDTH];
    __shared__ int s[BWIDTH];
    __shared__ int cur[BWIDTH];
    int tid = threadIdx.x;
    int b = blockIdx.x;
    int base = b << SHIFT;
    int e0 = bstart[b], e1 = bstart[b + 1];
    if (tid < BWIDTH) cnt[tid] = 0;
    __syncthreads();
    for (int e = e0 + tid; e < e1; e += 512)
        atomicAdd(&cnt[binned[e] >> 17], 1);
    __syncthreads();
    int v = 0;
    if (tid < BWIDTH) { v = cnt[tid]; s[tid] = v; }
    __syncthreads();
    for (int off = 1; off < BWIDTH; off <<= 1) {
        int t = 0;
        if (tid < BWIDTH && tid >= off) t = s[tid - off];
        __syncthreads();
        if (tid < BWIDTH) s[tid] += t;
        __syncthreads();
    }
    if (tid < BWIDTH) {
        int ex = s[tid] - v;
        cur[tid] = ex;
        int node = base + tid;
        if (node < N_NODES) {
            rp[node] = e0 + ex;
            dinv[node] = rsqrtf((float)(v + 1));
        }
    }
    if (b == 0 && tid == 0) rp[N_NODES] = N_EDGES;
    __syncthreads();
    for (int e = e0 + tid; e < e1; e += 512) {
        unsigned int w = binned[e];
        int ln = (int)(w >> 17);
        int p = atomicAdd(&cur[ln], 1);
        col[e0 + p] = (int)(w & 0x1FFFFu);
    }
}

// ---------------- h0s = dinv * (x @ W1): LDS-tiled GEMM, b128 reads ----------------
#define XW_ROWS 64
#define XW_KT   32
#define XW_S    36
#define XW_NT   (F_IN / XW_KT)   // 16 tiles
__global__ void k_xw1(const float* __restrict__ x, const float* __restrict__ W,
                      const float* __restrict__ dinv, float* __restrict__ h0s) {
    __shared__ float xT[2][XW_ROWS * XW_S];
    int tid = threadIdx.x;
    int rowBase = blockIdx.x * XW_ROWS;

    int rf0 = tid >> 3, kq = tid & 7;    // row 0..31, float4-col 0..7
    int rf1 = rf0 + 32;
    bool v0 = (rowBase + rf0) < N_NODES;
    bool v1 = (rowBase + rf1) < N_NODES;
    const float4* xrow0 = (const float4*)(x + (size_t)(rowBase + rf0) * F_IN);
    const float4* xrow1 = (const float4*)(x + (size_t)(rowBase + rf1) * F_IN);

    int r  = tid & 63;
    int cg = __builtin_amdgcn_readfirstlane(tid >> 6);   // wave-uniform -> s_load W
    const float4* W4 = (const float4*)W;

    float4 zero4 = make_float4(0.f, 0.f, 0.f, 0.f);
    float4 acc = zero4;
    float4 ld0 = v0 ? xrow0[kq] : zero4;
    float4 ld1 = v1 ? xrow1[kq] : zero4;

    for (int kt = 0; kt < XW_NT; kt++) {
        float* xb = xT[kt & 1];
        *(float4*)&xb[rf0 * XW_S + kq * 4] = ld0;
        *(float4*)&xb[rf1 * XW_S + kq * 4] = ld1;
        if (kt + 1 < XW_NT) {
            ld0 = v0 ? xrow0[(kt + 1) * 8 + kq] : zero4;
            ld1 = v1 ? xrow1[(kt + 1) * 8 + kq] : zero4;
        }
        __syncthreads();
        const float* xr = &xb[r * XW_S];
#pragma unroll
        for (int k8 = 0; k8 < 8; k8++) {
            float4 xv = *(const float4*)&xr[k8 * 4];
            float4 w0 = W4[(kt * XW_KT + k8 * 4 + 0) * 4 + cg];
            acc.x += xv.x * w0.x; acc.y += xv.x * w0.y;
            acc.z += xv.x * w0.z; acc.w += xv.x * w0.w;
            float4 w1 = W4[(kt * XW_KT + k8 * 4 + 1) * 4 + cg];
            acc.x += xv.y * w1.x; acc.y += xv.y * w1.y;
            acc.z += xv.y * w1.z; acc.w += xv.y * w1.w;
            float4 w2 = W4[(kt * XW_KT + k8 * 4 + 2) * 4 + cg];
            acc.x += xv.z * w2.x; acc.y += xv.z * w2.y;
            acc.z += xv.z * w2.z; acc.w += xv.z * w2.w;
            float4 w3 = W4[(kt * XW_KT + k8 * 4 + 3) * 4 + cg];
            acc.x += xv.w * w3.x; acc.y += xv.w * w3.y;
            acc.z += xv.w * w3.z; acc.w += xv.w * w3.w;
        }
        __syncthreads();
    }
    int node = rowBase + r;
    if (node < N_NODES) {
        float dv = dinv[node];
        float4 o;
        o.x = dv * acc.x; o.y = dv * acc.y; o.z = dv * acc.z; o.w = dv * acc.w;
        ((float4*)h0s)[(size_t)node * 4 + cg] = o;
    }
}

// ---------------- aggregate 1: one wave per node, x4 unroll ----------------
// lane = c + 16*eo; in-order adds; 16 independent gathers in flight per wave.
__global__ void k_agg1(const float* __restrict__ h0s, const int* __restrict__ rp,
                       const int* __restrict__ col, const float* __restrict__ dinv,
                       const float* __restrict__ b1, float* __restrict__ h1) {
    int node = (blockIdx.x * blockDim.x + threadIdx.x) >> 6;
    if (node >= N_NODES) return;
    int lane = threadIdx.x & 63;
    int c = lane & 15, eo = lane >> 4;
    int e0 = rp[node], e1 = rp[node + 1];
    float acc = 0.f;
    int e = e0 + eo;
    for (; e + 12 < e1; e += 16) {
        int c0 = col[e];
        int c1 = col[e + 4];
        int c2 = col[e + 8];
        int c3 = col[e + 12];
        float v0 = h0s[(size_t)c0 * HID + c];
        float v1 = h0s[(size_t)c1 * HID + c];
        float v2 = h0s[(size_t)c2 * HID + c];
        float v3 = h0s[(size_t)c3 * HID + c];
        acc += v0;
        acc += v1;
        acc += v2;
        acc += v3;
    }
    for (; e + 4 < e1; e += 8) {
        int c0 = col[e];
        int c1 = col[e + 4];
        float v0 = h0s[(size_t)c0 * HID + c];
        float v1 = h0s[(size_t)c1 * HID + c];
        acc += v0;
        acc += v1;
    }
    if (e < e1) acc += h0s[(size_t)col[e] * HID + c];
    acc += __shfl_xor(acc, 16);
    acc += __shfl_xor(acc, 32);
    float o = dinv[node] * (acc + h0s[(size_t)node * HID + c]) + b1[c];
    if (eo == 0) h1[(size_t)node * HID + c] = fmaxf(o, 0.f);
}

// ---------------- 10 fused hops + zs = dinv * (h @ W2) ----------------
__global__ void k_hops(const float* __restrict__ h1, const float* __restrict__ Wl,
                       const float* __restrict__ bl, const float* __restrict__ W2,
                       const float* __restrict__ dinv, float* __restrict__ zs) {
    int node = blockIdx.x * blockDim.x + threadIdx.x;
    if (node >= N_NODES) return;
    float h[HID];
    const float4* h4 = (const float4*)(h1 + (size_t)node * HID);
#pragma unroll
    for (int q = 0; q < HID / 4; q++) {
        float4 v = h4[q];
        h[q * 4 + 0] = v.x; h[q * 4 + 1] = v.y;
        h[q * 4 + 2] = v.z; h[q * 4 + 3] = v.w;
    }
    for (int it = 0; it < K_HOPS; it++) {
        float tm[HID];
#pragma unroll
        for (int c = 0; c < HID; c++) tm[c] = bl[c];
#pragma unroll
        for (int k = 0; k < HID; k++) {
            float hk = h[k];
#pragma unroll
            for (int c = 0; c < HID; c++) tm[c] += hk * Wl[k * HID + c];
        }
#pragma unroll
        for (int c = 0; c < HID; c++)
            h[c] = ALPHA * fmaxf(tm[c], 0.f) + (1.f - ALPHA) * h[c];
    }
    float dv = dinv[node];
    float zz[8];
#pragma unroll
    for (int c = 0; c < 8; c++) zz[c] = 0.f;
#pragma unroll
    for (int k = 0; k < HID; k++) {
        float hk = h[k];
#pragma unroll
        for (int c = 0; c < NCLS; c++) zz[c] += hk * W2[k * NCLS + c];
    }
    float4* z4 = (float4*)(zs + (size_t)node * 8);
    float4 v0, v1;
    v0.x = dv * zz[0]; v0.y = dv * zz[1]; v0.z = dv * zz[2]; v0.w = dv * zz[3];
    v1.x = dv * zz[4]; v1.y = dv * zz[5]; v1.z = dv * zz[6]; v1.w = 0.f;
    z4[0] = v0; z4[1] = v1;
}

// ---------------- aggregate 2 + log_softmax: one wave per node, x4 unroll ----------------
// lane = c + 8*eo; in-order adds; 32 independent gathers in flight per wave.
__global__ void k_agg2(const float* __restrict__ zs, const int* __restrict__ rp,
                       const int* __restrict__ col, const float* __restrict__ dinv,
                       const float* __restrict__ b2, float* __restrict__ out) {
    int node = (blockIdx.x * blockDim.x + threadIdx.x) >> 6;
    if (node >= N_NODES) return;
    int lane = threadIdx.x & 63;
    int c = lane & 7, eo = lane >> 3;
    int e0 = rp[node], e1 = rp[node + 1];
    float acc = 0.f;
    int e = e0 + eo;
    for (; e + 24 < e1; e += 32) {
        int c0 = col[e];
        int c1 = col[e + 8];
        int c2 = col[e + 16];
        int c3 = col[e + 24];
        float v0 = zs[(size_t)c0 * 8 + c];
        float v1 = zs[(size_t)c1 * 8 + c];
        float v2 = zs[(size_t)c2 * 8 + c];
        float v3 = zs[(size_t)c3 * 8 + c];
        acc += v0;
        acc += v1;
        acc += v2;
        acc += v3;
    }
    for (; e + 8 < e1; e += 16) {
        int c0 = col[e];
        int c1 = col[e + 8];
        float v0 = zs[(size_t)c0 * 8 + c];
        float v1 = zs[(size_t)c1 * 8 + c];
        acc += v0;
        acc += v1;
    }
    if (e < e1) acc += zs[(size_t)col[e] * 8 + c];
    acc += __shfl_xor(acc, 8);
    acc += __shfl_xor(acc, 16);
    acc += __shfl_xor(acc, 32);
    float o = dinv[node] * (acc + zs[(size_t)node * 8 + c]) + ((c < NCLS) ? b2[c] : 0.f);
    float val = (c < NCLS) ? o : -INFINITY;
    float m = val;
    m = fmaxf(m, __shfl_xor(m, 1));
    m = fmaxf(m, __shfl_xor(m, 2));
    m = fmaxf(m, __shfl_xor(m, 4));
    float ex = (c < NCLS) ? expf(o - m) : 0.f;
    float ss = ex;
    ss += __shfl_xor(ss, 1);
    ss += __shfl_xor(ss, 2);
    ss += __shfl_xor(ss, 4);
    if (eo == 0 && c < NCLS) out[(size_t)node * NCLS + c] = o - m - logf(ss);
}

extern "C" void kernel_launch(void* const* d_in, const int* in_sizes, int n_in,
                              void* d_out, int out_size, void* d_ws, size_t ws_size,
                              hipStream_t stream) {
    const float* x  = (const float*)d_in[0];
    const int*   ei = (const int*)d_in[1];
    const float* W1 = (const float*)d_in[2];
    const float* b1 = (const float*)d_in[3];
    const float* Wl = (const float*)d_in[4];
    const float* bl = (const float*)d_in[5];
    const float* W2 = (const float*)d_in[6];
    const float* b2 = (const float*)d_in[7];
    float* out = (float*)d_out;

    int*   wsI = (int*)d_ws;
    float* wsF = (float*)d_ws;
    int*          bcnt   = wsI + OFF_BCNT;
    int*          bstart = wsI + OFF_BSTART;
    int*          bcur   = wsI + OFF_BCUR;
    int*          rp     = wsI + OFF_RP;
    float*        dinv   = wsF + OFF_DINV;
    int*          col    = wsI + OFF_COL;
    unsigned int* binned = (unsigned int*)(wsI + OFF_BINNED);
    float*        h0s    = wsF + OFF_H0;
    float*        h1     = wsF + OFF_H1;
    float*        zs     = wsF + OFF_Z;

    const int* src = ei;
    const int* dst = ei + N_EDGES;

    hipMemsetAsync(bcnt, 0, NBUCK * sizeof(int), stream);

    k_bhist<<<1024, 256, 0, stream>>>(dst, bcnt);
    k_bscan<<<1, 1024, 0, stream>>>(bcnt, bstart, bcur);
    k_bin<<<A3_BLOCKS, BIN_T, 0, stream>>>(src, dst, bcur, binned);
    k_csr<<<NBUCK, 512, 0, stream>>>(binned, bstart, rp, dinv, col);
    k_xw1<<<(N_NODES + XW_ROWS - 1) / XW_ROWS, 256, 0, stream>>>(x, W1, dinv, h0s);
    k_agg1<<<(N_NODES * 64 + 255) / 256, 256, 0, stream>>>(h0s, rp, col, dinv, b1, h1);
    k_hops<<<(N_NODES + 255) / 256, 256, 0, stream>>>(h1, Wl, bl, W2, dinv, zs);
    k_agg2<<<(N_NODES * 64 + 255) / 256, 256, 0, stream>>>(zs, rp, col, dinv, b2, out);
}